// Round 7
// baseline (48960.995 us; speedup 1.0000x reference)
//
#include <hip/hip_runtime.h>
#include <stdint.h>
#include <stddef.h>

// LSTMNetwork: 3-layer stacked LSTM, batch=1, T=4096, IN=64, H=1024, OUT=1.
// fp32 in/out (verified round 6: absmax 0.0).
//
// Round 7: single-launch 3-layer WAVEFRONT PIPELINE + incremental polling.
//  - 768 blocks x 256 thr, __launch_bounds__(256,3) => 3 blocks/CU, all
//    co-resident (required: layer l+1 polls layer l's output live).
//  - One wave per (layer, hidden unit). Weights in VGPRs/AGPRs (fp32).
//  - Exchange: 64-bit tagged slots [tag32|fp32], relaxed agent-scope atomics.
//    Layers 0/1 publish full history (no overwrite -> no flow control);
//    layer 2 publishes into a 16-row ring (self-consumed 1 step later, 14-row
//    safety margin).
//  - Incremental poll: per-lane todo bitmask, re-load only stale slots, FMA
//    each slot once (round 6 re-read the full 8 KB row every pass ->
//    L2-bandwidth-saturated polling, 3.48 us/step).

#define T_STEPS 4096
#define HD      1024
#define RINGR   16

#define TAGL0 0x10000000u
#define TAGL1 0x30000000u
#define TAGL2 0x50000000u

typedef unsigned long long u64;

// ~64.1 MB module .bss -- harness never pokes these.
__device__ u64 g_bufA[(size_t)T_STEPS * HD];  // layer0 h history (32 MB)
__device__ u64 g_bufB[(size_t)T_STEPS * HD];  // layer1 h history (32 MB)
__device__ u64 g_ring[RINGR * HD];            // layer2 ring (128 KB)

__global__ __launch_bounds__(256)
void zero_bufs()
{
    const size_t gtid = (size_t)blockIdx.x * blockDim.x + threadIdx.x;
    const size_t step = (size_t)gridDim.x * blockDim.x;
    for (size_t i = gtid; i < (size_t)T_STEPS * HD; i += step) g_bufA[i] = 0ULL;
    for (size_t i = gtid; i < (size_t)T_STEPS * HD; i += step) g_bufB[i] = 0ULL;
    for (size_t i = gtid; i < (size_t)RINGR * HD;  i += step) g_ring[i] = 0ULL;
}

__global__ __launch_bounds__(256, 3)   // 3 waves/EU => 3 blocks/CU => 768 resident
void fused_scan(const float* __restrict__ seq,
                const float* __restrict__ wih0, const float* __restrict__ whh0,
                const float* __restrict__ bih0, const float* __restrict__ bhh0,
                const float* __restrict__ wih1, const float* __restrict__ whh1,
                const float* __restrict__ bih1, const float* __restrict__ bhh1,
                const float* __restrict__ wih2, const float* __restrict__ whh2,
                const float* __restrict__ bih2, const float* __restrict__ bhh2)
{
    const int layer = blockIdx.x >> 8;           // 0,1,2
    const int bu    = blockIdx.x & 255;
    const int lane  = threadIdx.x & 63;
    const int wave  = threadIdx.x >> 6;
    const int j     = bu * 4 + wave;             // hidden unit of this wave

    const float* w_ih = (layer == 0) ? wih0 : (layer == 1) ? wih1 : wih2;
    const float* w_hh = (layer == 0) ? whh0 : (layer == 1) ? whh1 : whh2;
    const float* b_ih = (layer == 0) ? bih0 : (layer == 1) ? bih1 : bih2;
    const float* b_hh = (layer == 0) ? bhh0 : (layer == 1) ? bhh1 : bhh2;

    u64*           hout   = (layer == 0) ? g_bufA : (layer == 1) ? g_bufB : g_ring;
    const u64*     xin    = (layer == 1) ? g_bufA : g_bufB;       // layer0: unused
    const uint32_t mybase = (layer == 0) ? TAGL0 : (layer == 1) ? TAGL1 : TAGL2;
    const uint32_t xbase  = (layer == 1) ? TAGL0 : TAGL1;         // layer0: unused
    const uint32_t rowm   = (layer == 2) ? (RINGR - 1) : 0xFFFFFFFFu;

    const int r0 = 0 * HD + j;   // i gate row
    const int r1 = 1 * HD + j;   // f
    const int r2 = 2 * HD + j;   // g
    const int r3 = 3 * HD + j;   // o

    // ---- weights into registers ----
    float whhr0[16], whhr1[16], whhr2[16], whhr3[16];
    {
        const float* p0 = w_hh + (size_t)r0 * HD;
        const float* p1 = w_hh + (size_t)r1 * HD;
        const float* p2 = w_hh + (size_t)r2 * HD;
        const float* p3 = w_hh + (size_t)r3 * HD;
#pragma unroll
        for (int i = 0; i < 16; ++i) {
            whhr0[i] = p0[64 * i + lane];
            whhr1[i] = p1[64 * i + lane];
            whhr2[i] = p2[64 * i + lane];
            whhr3[i] = p3[64 * i + lane];
        }
    }
    float wihr0[16], wihr1[16], wihr2[16], wihr3[16];             // layers 1/2
    float wi0v0 = 0.f, wi0v1 = 0.f, wi0v2 = 0.f, wi0v3 = 0.f;     // layer 0
    if (layer != 0) {
        const float* p0 = w_ih + (size_t)r0 * HD;
        const float* p1 = w_ih + (size_t)r1 * HD;
        const float* p2 = w_ih + (size_t)r2 * HD;
        const float* p3 = w_ih + (size_t)r3 * HD;
#pragma unroll
        for (int i = 0; i < 16; ++i) {
            wihr0[i] = p0[64 * i + lane];
            wihr1[i] = p1[64 * i + lane];
            wihr2[i] = p2[64 * i + lane];
            wihr3[i] = p3[64 * i + lane];
        }
    } else {
        wi0v0 = w_ih[(size_t)r0 * 64 + lane];
        wi0v1 = w_ih[(size_t)r1 * 64 + lane];
        wi0v2 = w_ih[(size_t)r2 * 64 + lane];
        wi0v3 = w_ih[(size_t)r3 * 64 + lane];
    }

    const float bias0 = b_ih[r0] + b_hh[r0];
    const float bias1 = b_ih[r1] + b_hh[r1];
    const float bias2 = b_ih[r2] + b_hh[r2];
    const float bias3 = b_ih[r3] + b_hh[r3];

    float c = 0.0f;

    for (int t = 0; t < T_STEPS; ++t) {
        float a0, a1, a2, a3;
        if (layer == 0) {
            const float xv = seq[(size_t)t * 64 + lane];
            a0 = wi0v0 * xv; a1 = wi0v1 * xv; a2 = wi0v2 * xv; a3 = wi0v3 * xv;
        } else {
            a0 = a1 = a2 = a3 = 0.f;
        }

        // ---- incremental poll: x-row (layers 1/2) + own h-row (t>0) ----
        uint32_t todo_x = (layer == 0) ? 0u : 0xFFFFu;
        uint32_t todo_h = (t > 0) ? 0xFFFFu : 0u;
        const uint32_t xtag = xbase + (uint32_t)t;
        const uint32_t htag = mybase + (uint32_t)(t - 1);
        const u64* xrow = xin + (size_t)t * HD;
        const u64* hrow = hout + (size_t)((uint32_t)(t - 1) & rowm) * HD;

        while (__any(todo_x | todo_h)) {
#pragma unroll
            for (int i = 0; i < 16; ++i) {
                if (todo_x & (1u << i)) {
                    const u64 u = __hip_atomic_load(xrow + 64 * i + lane,
                                                    __ATOMIC_RELAXED,
                                                    __HIP_MEMORY_SCOPE_AGENT);
                    if ((uint32_t)(u >> 32) == xtag) {
                        const float xv = __uint_as_float((uint32_t)u);
                        a0 = __fmaf_rn(wihr0[i], xv, a0);
                        a1 = __fmaf_rn(wihr1[i], xv, a1);
                        a2 = __fmaf_rn(wihr2[i], xv, a2);
                        a3 = __fmaf_rn(wihr3[i], xv, a3);
                        todo_x &= ~(1u << i);
                    }
                }
            }
#pragma unroll
            for (int i = 0; i < 16; ++i) {
                if (todo_h & (1u << i)) {
                    const u64 u = __hip_atomic_load(hrow + 64 * i + lane,
                                                    __ATOMIC_RELAXED,
                                                    __HIP_MEMORY_SCOPE_AGENT);
                    if ((uint32_t)(u >> 32) == htag) {
                        const float hv = __uint_as_float((uint32_t)u);
                        a0 = __fmaf_rn(whhr0[i], hv, a0);
                        a1 = __fmaf_rn(whhr1[i], hv, a1);
                        a2 = __fmaf_rn(whhr2[i], hv, a2);
                        a3 = __fmaf_rn(whhr3[i], hv, a3);
                        todo_h &= ~(1u << i);
                    }
                }
            }
        }

        // ---- reduce 4 gate dot-products across 64 lanes ----
#pragma unroll
        for (int m = 1; m < 64; m <<= 1) {
            a0 += __shfl_xor(a0, m, 64);
            a1 += __shfl_xor(a1, m, 64);
            a2 += __shfl_xor(a2, m, 64);
            a3 += __shfl_xor(a3, m, 64);
        }

        // ---- lane-0 epilogue: activations, state, publish ----
        if (lane == 0) {
            const float ig = 1.0f / (1.0f + expf(-(a0 + bias0)));
            const float fg = 1.0f / (1.0f + expf(-(a1 + bias1)));
            const float gg = tanhf(a2 + bias2);
            const float og = 1.0f / (1.0f + expf(-(a3 + bias3)));
            c = fg * c + ig * gg;
            const float h = og * tanhf(c);
            const u64 slot = ((u64)(mybase + (uint32_t)t) << 32)
                           | (u64)__float_as_uint(h);
            __hip_atomic_store(hout + (size_t)((uint32_t)t & rowm) * HD + j, slot,
                               __ATOMIC_RELAXED, __HIP_MEMORY_SCOPE_AGENT);
        }
    }
}

__global__ __launch_bounds__(256)
void final_kernel(const float* __restrict__ w_lin,
                  const float* __restrict__ b_lin,
                  float*       __restrict__ out)
{
    __shared__ float red[256];
    const int tid = threadIdx.x;
    const u64* hrow = g_ring + (size_t)((T_STEPS - 1) & (RINGR - 1)) * HD;
    float s = 0.f;
#pragma unroll
    for (int i = 0; i < 4; ++i) {
        const int k = tid + 256 * i;
        s += __uint_as_float((uint32_t)hrow[k]) * w_lin[k];
    }
    red[tid] = s;
    __syncthreads();
    for (int o = 128; o > 0; o >>= 1) {
        if (tid < o) red[tid] += red[tid + o];
        __syncthreads();
    }
    if (tid == 0) out[0] = red[0] + b_lin[0];
}

extern "C" void kernel_launch(void* const* d_in, const int* in_sizes, int n_in,
                              void* d_out, int out_size, void* d_ws, size_t ws_size,
                              hipStream_t stream)
{
    (void)in_sizes; (void)n_in; (void)out_size; (void)d_ws; (void)ws_size;

    const float* seq   = (const float*)d_in[0];
    const float* w_ih0 = (const float*)d_in[1];
    const float* w_hh0 = (const float*)d_in[2];
    const float* b_ih0 = (const float*)d_in[3];
    const float* b_hh0 = (const float*)d_in[4];
    const float* w_ih1 = (const float*)d_in[5];
    const float* w_hh1 = (const float*)d_in[6];
    const float* b_ih1 = (const float*)d_in[7];
    const float* b_hh1 = (const float*)d_in[8];
    const float* w_ih2 = (const float*)d_in[9];
    const float* w_hh2 = (const float*)d_in[10];
    const float* b_ih2 = (const float*)d_in[11];
    const float* b_hh2 = (const float*)d_in[12];
    const float* w_lin = (const float*)d_in[13];
    const float* b_lin = (const float*)d_in[14];

    // Tag hygiene (stale tags from the previous replay would alias).
    zero_bufs<<<dim3(1024), dim3(256), 0, stream>>>();

    // All 3 layers pipelined in one launch: blocks [0,256)=L0, [256,512)=L1,
    // [512,768)=L2; 3 blocks/CU co-resident via __launch_bounds__(256,3).
    fused_scan<<<dim3(768), dim3(256), 0, stream>>>(
        seq,
        w_ih0, w_hh0, b_ih0, b_hh0,
        w_ih1, w_hh1, b_ih1, b_hh1,
        w_ih2, w_hh2, b_ih2, b_hh2);

    final_kernel<<<dim3(1), dim3(256), 0, stream>>>(w_lin, b_lin, (float*)d_out);
}

// Round 8
// 31261.557 us; speedup vs baseline: 1.5662x; 1.5662x over previous
//
#include <hip/hip_runtime.h>
#include <stdint.h>
#include <stddef.h>

// LSTMNetwork: 3-layer stacked LSTM, batch=1, T=4096, IN=64, H=1024, OUT=1.
// fp32 in/out (verified: absmax 0.0 rounds 6/7).
//
// Round 8: fused 3-layer wavefront pipeline + cooperative LDS staging.
//   Round 7 failed on (a) scratch spill (WRITE_SIZE +360 MB: 128 weight floats
//   + 32 live probe temps > 170-reg cap at 3 blocks/CU) and (b) probe
//   bandwidth congestion (~48 MB/pass of agent-scope LLC probes).
//   Fix: per block, wave w polls only its quarter of each slot row and stages
//   fp32 values into double-buffered LDS; __syncthreads(); all 4 waves FMA
//   from LDS. Probe traffic /4, staging phase holds no weights, compute phase
//   is LDS-read+FMA -> fits 170 regs without spill.
//  - 768 blocks x 256 thr, __launch_bounds__(256,3): 3 blocks/CU co-resident
//    (guaranteed by the bound even if it must spill -> no deadlock risk).
//  - Exchange: 64-bit tagged slots [tag32|fp32], relaxed agent-scope atomics.
//    Layers 0/1 keep full history (cross-layer consumers may lag arbitrarily);
//    layer 2 uses a 16-row ring (self-consumers skew <= 1 step: a block at
//    step t implies ALL layer-2 blocks published t-1).

#define T_STEPS 4096
#define HD      1024
#define RINGR   16

#define TAGL0 0x10000000u
#define TAGL1 0x30000000u
#define TAGL2 0x50000000u

typedef unsigned long long u64;

// ~64.1 MB module .bss -- harness never pokes these.
__device__ u64 g_bufA[(size_t)T_STEPS * HD];  // layer0 h history (32 MB)
__device__ u64 g_bufB[(size_t)T_STEPS * HD];  // layer1 h history (32 MB)
__device__ u64 g_ring[RINGR * HD];            // layer2 ring (128 KB)

__device__ __forceinline__ float fsig(float x)  { return 1.0f / (1.0f + __expf(-x)); }
__device__ __forceinline__ float ftanh(float x) { return 1.0f - 2.0f / (__expf(2.0f * x) + 1.0f); }

__global__ __launch_bounds__(256)
void zero_bufs()
{
    const size_t gtid = (size_t)blockIdx.x * blockDim.x + threadIdx.x;
    const size_t step = (size_t)gridDim.x * blockDim.x;
    for (size_t i = gtid; i < (size_t)T_STEPS * HD; i += step) g_bufA[i] = 0ULL;
    for (size_t i = gtid; i < (size_t)T_STEPS * HD; i += step) g_bufB[i] = 0ULL;
    for (size_t i = gtid; i < (size_t)RINGR * HD;  i += step) g_ring[i] = 0ULL;
}

__global__ __launch_bounds__(256, 3)   // 3 blocks/CU => all 768 co-resident
void fused_scan(const float* __restrict__ seq,
                const float* __restrict__ wih0, const float* __restrict__ whh0_,
                const float* __restrict__ bih0, const float* __restrict__ bhh0,
                const float* __restrict__ wih1, const float* __restrict__ whh1_,
                const float* __restrict__ bih1, const float* __restrict__ bhh1,
                const float* __restrict__ wih2, const float* __restrict__ whh2_,
                const float* __restrict__ bih2, const float* __restrict__ bhh2)
{
    __shared__ float s_x[2][HD];   // staged x row (layers 1/2)
    __shared__ float s_h[2][HD];   // staged own h[t-1] row

    const int layer = blockIdx.x >> 8;           // 0,1,2
    const int bu    = blockIdx.x & 255;
    const int lane  = threadIdx.x & 63;
    const int wave  = threadIdx.x >> 6;
    const int j     = bu * 4 + wave;             // hidden unit of this wave

    const float* w_ih = (layer == 0) ? wih0 : (layer == 1) ? wih1 : wih2;
    const float* w_hh = (layer == 0) ? whh0_ : (layer == 1) ? whh1_ : whh2_;
    const float* b_ih = (layer == 0) ? bih0 : (layer == 1) ? bih1 : bih2;
    const float* b_hh = (layer == 0) ? bhh0 : (layer == 1) ? bhh1 : bhh2;

    u64*           hout   = (layer == 0) ? g_bufA : (layer == 1) ? g_bufB : g_ring;
    const u64*     xin    = (layer == 1) ? g_bufA : g_bufB;       // layer0: unused
    const uint32_t mybase = (layer == 0) ? TAGL0 : (layer == 1) ? TAGL1 : TAGL2;
    const uint32_t xbase  = (layer == 1) ? TAGL0 : TAGL1;         // layer0: unused
    const uint32_t rowm   = (layer == 2) ? (RINGR - 1) : 0xFFFFFFFFu;

    const int r0 = 0 * HD + j;   // i gate row
    const int r1 = 1 * HD + j;   // f
    const int r2 = 2 * HD + j;   // g
    const int r3 = 3 * HD + j;   // o

    // ---- weights into registers ----
    float whhr0[16], whhr1[16], whhr2[16], whhr3[16];
    {
        const float* p0 = w_hh + (size_t)r0 * HD;
        const float* p1 = w_hh + (size_t)r1 * HD;
        const float* p2 = w_hh + (size_t)r2 * HD;
        const float* p3 = w_hh + (size_t)r3 * HD;
#pragma unroll
        for (int i = 0; i < 16; ++i) {
            whhr0[i] = p0[64 * i + lane];
            whhr1[i] = p1[64 * i + lane];
            whhr2[i] = p2[64 * i + lane];
            whhr3[i] = p3[64 * i + lane];
        }
    }
    float wihr0[16], wihr1[16], wihr2[16], wihr3[16];             // layers 1/2
    float wi0v0 = 0.f, wi0v1 = 0.f, wi0v2 = 0.f, wi0v3 = 0.f;     // layer 0
    if (layer != 0) {
        const float* p0 = w_ih + (size_t)r0 * HD;
        const float* p1 = w_ih + (size_t)r1 * HD;
        const float* p2 = w_ih + (size_t)r2 * HD;
        const float* p3 = w_ih + (size_t)r3 * HD;
#pragma unroll
        for (int i = 0; i < 16; ++i) {
            wihr0[i] = p0[64 * i + lane];
            wihr1[i] = p1[64 * i + lane];
            wihr2[i] = p2[64 * i + lane];
            wihr3[i] = p3[64 * i + lane];
        }
    } else {
        wi0v0 = w_ih[(size_t)r0 * 64 + lane];
        wi0v1 = w_ih[(size_t)r1 * 64 + lane];
        wi0v2 = w_ih[(size_t)r2 * 64 + lane];
        wi0v3 = w_ih[(size_t)r3 * 64 + lane];
    }

    const float bias0 = b_ih[r0] + b_hh[r0];
    const float bias1 = b_ih[r1] + b_hh[r1];
    const float bias2 = b_ih[r2] + b_hh[r2];
    const float bias3 = b_ih[r3] + b_hh[r3];

    float c = 0.0f;
    const int sb = wave << 8;    // this wave's staging quarter: elements [sb, sb+256)

    for (int t = 0; t < T_STEPS; ++t) {
        const int p = t & 1;

        // ---- phase 1: cooperative staging (no weights live here) ----
        {
            uint32_t todo = 0;
            if (layer != 0) todo |= 0x0Fu;          // x groups (bits 0..3)
            if (t > 0)      todo |= 0xF0u;          // h groups (bits 4..7)
            const uint32_t xtag = xbase + (uint32_t)t;
            const uint32_t htag = mybase + (uint32_t)(t - 1);
            const uint32_t hrowi = (t > 0) ? ((uint32_t)(t - 1) & rowm) : 0u;
            const u64* xrow = xin  + (size_t)t * HD;
            const u64* hrow = hout + (size_t)hrowi * HD;

            while (__any(todo)) {
#pragma unroll
                for (int i = 0; i < 4; ++i) {
                    const int e = sb + (i << 6) + lane;   // element index
                    if (todo & (1u << i)) {
                        const u64 u = __hip_atomic_load(xrow + e, __ATOMIC_RELAXED,
                                                        __HIP_MEMORY_SCOPE_AGENT);
                        if ((uint32_t)(u >> 32) == xtag) {
                            s_x[p][e] = __uint_as_float((uint32_t)u);
                            todo &= ~(1u << i);
                        }
                    }
                    if (todo & (1u << (4 + i))) {
                        const u64 u = __hip_atomic_load(hrow + e, __ATOMIC_RELAXED,
                                                        __HIP_MEMORY_SCOPE_AGENT);
                        if ((uint32_t)(u >> 32) == htag) {
                            s_h[p][e] = __uint_as_float((uint32_t)u);
                            todo &= ~(1u << (4 + i));
                        }
                    }
                }
            }
        }
        __syncthreads();

        // ---- phase 2: compute from LDS ----
        float a0, a1, a2, a3;
        if (layer == 0) {
            const float xv = seq[(size_t)t * 64 + lane];
            a0 = wi0v0 * xv; a1 = wi0v1 * xv; a2 = wi0v2 * xv; a3 = wi0v3 * xv;
        } else {
            a0 = a1 = a2 = a3 = 0.f;
            const float* sxp = s_x[p];
#pragma unroll
            for (int i = 0; i < 16; ++i) {
                const float xv = sxp[(i << 6) | lane];
                a0 = __fmaf_rn(wihr0[i], xv, a0);
                a1 = __fmaf_rn(wihr1[i], xv, a1);
                a2 = __fmaf_rn(wihr2[i], xv, a2);
                a3 = __fmaf_rn(wihr3[i], xv, a3);
            }
        }
        if (t > 0) {
            const float* shp = s_h[p];
#pragma unroll
            for (int i = 0; i < 16; ++i) {
                const float hv = shp[(i << 6) | lane];
                a0 = __fmaf_rn(whhr0[i], hv, a0);
                a1 = __fmaf_rn(whhr1[i], hv, a1);
                a2 = __fmaf_rn(whhr2[i], hv, a2);
                a3 = __fmaf_rn(whhr3[i], hv, a3);
            }
        }

        // ---- reduce 4 gate dot-products across 64 lanes ----
#pragma unroll
        for (int m = 1; m < 64; m <<= 1) {
            a0 += __shfl_xor(a0, m, 64);
            a1 += __shfl_xor(a1, m, 64);
            a2 += __shfl_xor(a2, m, 64);
            a3 += __shfl_xor(a3, m, 64);
        }

        // ---- epilogue: all lanes redundantly (no lane-0 serialization) ----
        const float ig = fsig(a0 + bias0);
        const float fg = fsig(a1 + bias1);
        const float gg = ftanh(a2 + bias2);
        const float og = fsig(a3 + bias3);
        c = fg * c + ig * gg;
        const float h = og * ftanh(c);
        if (lane == 0) {
            const u64 slot = ((u64)(mybase + (uint32_t)t) << 32)
                           | (u64)__float_as_uint(h);
            __hip_atomic_store(hout + (size_t)((uint32_t)t & rowm) * HD + j, slot,
                               __ATOMIC_RELAXED, __HIP_MEMORY_SCOPE_AGENT);
        }
    }
}

__global__ __launch_bounds__(256)
void final_kernel(const float* __restrict__ w_lin,
                  const float* __restrict__ b_lin,
                  float*       __restrict__ out)
{
    __shared__ float red[256];
    const int tid = threadIdx.x;
    const u64* hrow = g_ring + (size_t)((T_STEPS - 1) & (RINGR - 1)) * HD;
    float s = 0.f;
#pragma unroll
    for (int i = 0; i < 4; ++i) {
        const int k = tid + 256 * i;
        s += __uint_as_float((uint32_t)hrow[k]) * w_lin[k];
    }
    red[tid] = s;
    __syncthreads();
    for (int o = 128; o > 0; o >>= 1) {
        if (tid < o) red[tid] += red[tid + o];
        __syncthreads();
    }
    if (tid == 0) out[0] = red[0] + b_lin[0];
}

extern "C" void kernel_launch(void* const* d_in, const int* in_sizes, int n_in,
                              void* d_out, int out_size, void* d_ws, size_t ws_size,
                              hipStream_t stream)
{
    (void)in_sizes; (void)n_in; (void)out_size; (void)d_ws; (void)ws_size;

    const float* seq   = (const float*)d_in[0];
    const float* w_ih0 = (const float*)d_in[1];
    const float* w_hh0 = (const float*)d_in[2];
    const float* b_ih0 = (const float*)d_in[3];
    const float* b_hh0 = (const float*)d_in[4];
    const float* w_ih1 = (const float*)d_in[5];
    const float* w_hh1 = (const float*)d_in[6];
    const float* b_ih1 = (const float*)d_in[7];
    const float* b_hh1 = (const float*)d_in[8];
    const float* w_ih2 = (const float*)d_in[9];
    const float* w_hh2 = (const float*)d_in[10];
    const float* b_ih2 = (const float*)d_in[11];
    const float* b_hh2 = (const float*)d_in[12];
    const float* w_lin = (const float*)d_in[13];
    const float* b_lin = (const float*)d_in[14];

    // Tag hygiene (previous replay left matching tags in the buffers).
    zero_bufs<<<dim3(1024), dim3(256), 0, stream>>>();

    // Blocks [0,256)=L0, [256,512)=L1, [512,768)=L2; 3 blocks/CU.
    fused_scan<<<dim3(768), dim3(256), 0, stream>>>(
        seq,
        w_ih0, w_hh0, b_ih0, b_hh0,
        w_ih1, w_hh1, b_ih1, b_hh1,
        w_ih2, w_hh2, b_ih2, b_hh2);

    final_kernel<<<dim3(1), dim3(256), 0, stream>>>(w_lin, b_lin, (float*)d_out);
}